// Round 1
// baseline (120.253 us; speedup 1.0000x reference)
//
#include <hip/hip_runtime.h>

// QuerySpecificClusterModel: B=256 samples, n=64 points, d=768.
// Per sample: scaled[i,:] = q * psg[i,:]; D = pairwise Euclid of scaled rows;
// single-linkage cluster to k=#unique(labels); scalar loss.
//
// Kernel 1 (fused, 1 block/sample, 256 thr):
//   phase 1: Gram G = S·S^T via LDS chunks (CH=128, XOR-swizzle), 8x8 reg
//            tiles, K split over 4 waves, cross-wave LDS reduce.
//   phase 2: wave 0 builds D in LDS (diag exactly 0), runs single-linkage
//            with per-row (minval,minidx) maintenance + butterfly argmin,
//            exact jnp.argmin lowest-flat-index tie-breaking.
//   outputs per-sample: simSum, disSum, simCnt, errCnt -> d_ws
// Kernel 2: deterministic 64-lane reduction over 256 samples -> d_out[0].

#define NBLK 256
#define NPTS 64
#define DIM 768
#define CH 128
#define NCH (DIM / CH)     // 6
#define BIGF 1e9f

__global__ __launch_bounds__(256) void fused_kernel(
    const float* __restrict__ q,      // [256,768]
    const float* __restrict__ psg,    // [256,64,768]
    const int*   __restrict__ labels, // [256,64]
    float* __restrict__ simS_o, float* __restrict__ disS_o,
    int* __restrict__ simC_o, int* __restrict__ errC_o)
{
  __shared__ __align__(16) float s[NPTS][132];   // staged scaled chunk (swizzled)
  __shared__ float Dw[NPTS][65];                 // distance matrix (65-pad: conflict-free)
  __shared__ float diag[NPTS];

  const int b = blockIdx.x;
  const int t = threadIdx.x;
  const int w = t >> 6;          // wave id 0..3
  const int lane = t & 63;
  const int g = lane >> 3;       // 8x8 tile-grid row
  const int h = lane & 7;        // 8x8 tile-grid col
  const int i0 = g << 3;
  const int j0 = h << 3;

  const float* qb = q + (size_t)b * DIM;
  const float* pb = psg + (size_t)b * NPTS * DIM;

  float acc[8][8];
  #pragma unroll
  for (int ii = 0; ii < 8; ++ii)
    #pragma unroll
    for (int jj = 0; jj < 8; ++jj) acc[ii][jj] = 0.f;

  const int kvq = t & 31;        // float4 col within chunk (staging)
  const int irb = t >> 5;        // staging row base 0..7

  for (int c = 0; c < NCH; ++c) {
    // q chunk fragment for this thread's staging column (coalesced)
    float4 qv = *reinterpret_cast<const float4*>(qb + c * CH + (kvq << 2));
    #pragma unroll
    for (int r = 0; r < 8; ++r) {
      int i = irb + (r << 3);    // row 0..63
      float4 pv = *reinterpret_cast<const float4*>(pb + (size_t)i * DIM + c * CH + (kvq << 2));
      float4 sv;
      sv.x = pv.x * qv.x; sv.y = pv.y * qv.y;
      sv.z = pv.z * qv.z; sv.w = pv.w * qv.w;
      int kws = kvq ^ ((i >> 2) & 7);            // bank-conflict XOR swizzle
      *reinterpret_cast<float4*>(&s[i][kws << 2]) = sv;
    }
    __syncthreads();

    // K split across waves: wave w owns k4 = w*8 .. w*8+7 of this chunk
    #pragma unroll 1
    for (int kk = 0; kk < 8; ++kk) {
      int k4 = (w << 3) + kk;
      float4 a4[8];
      #pragma unroll
      for (int ii = 0; ii < 8; ++ii) {
        int row = i0 + ii;
        int kA = (k4 ^ ((row >> 2) & 7)) << 2;
        a4[ii] = *reinterpret_cast<const float4*>(&s[row][kA]);
      }
      #pragma unroll
      for (int jj = 0; jj < 8; ++jj) {
        int row = j0 + jj;
        int kB = (k4 ^ ((row >> 2) & 7)) << 2;
        float4 b4 = *reinterpret_cast<const float4*>(&s[row][kB]);
        #pragma unroll
        for (int ii = 0; ii < 8; ++ii) {
          acc[ii][jj] += a4[ii].x * b4.x;
          acc[ii][jj] += a4[ii].y * b4.y;
          acc[ii][jj] += a4[ii].z * b4.z;
          acc[ii][jj] += a4[ii].w * b4.w;
        }
      }
    }
    __syncthreads();
  }

  // Cross-wave reduction of partial Gram into wave 0 (fixed order: src 1,2,3)
  float* fs = &s[0][0];
  #pragma unroll 1
  for (int src = 1; src < 4; ++src) {
    if (w == src) {
      #pragma unroll
      for (int ii = 0; ii < 8; ++ii) {
        #pragma unroll
        for (int jq = 0; jq < 2; ++jq) {
          float4 vv;
          vv.x = acc[ii][jq * 4 + 0]; vv.y = acc[ii][jq * 4 + 1];
          vv.z = acc[ii][jq * 4 + 2]; vv.w = acc[ii][jq * 4 + 3];
          *reinterpret_cast<float4*>(&fs[(lane << 6) + (ii << 3) + (jq << 2)]) = vv;
        }
      }
    }
    __syncthreads();
    if (w == 0) {
      #pragma unroll
      for (int ii = 0; ii < 8; ++ii) {
        #pragma unroll
        for (int jq = 0; jq < 2; ++jq) {
          float4 vv = *reinterpret_cast<const float4*>(&fs[(lane << 6) + (ii << 3) + (jq << 2)]);
          acc[ii][jq * 4 + 0] += vv.x; acc[ii][jq * 4 + 1] += vv.y;
          acc[ii][jq * 4 + 2] += vv.z; acc[ii][jq * 4 + 3] += vv.w;
        }
      }
    }
    __syncthreads();
  }

  // diag (squared norms) from diagonal tiles
  if (w == 0 && g == h) {
    #pragma unroll
    for (int ii = 0; ii < 8; ++ii) diag[i0 + ii] = acc[ii][ii];
  }
  __syncthreads();

  // Distances into Dw (wave 0 holds the reduced Gram)
  if (w == 0) {
    #pragma unroll
    for (int ii = 0; ii < 8; ++ii) {
      float di = diag[i0 + ii];
      #pragma unroll
      for (int jj = 0; jj < 8; ++jj) {
        float d2 = di + diag[j0 + jj] - 2.f * acc[ii][jj];
        d2 = fmaxf(d2, 0.f);
        Dw[i0 + ii][j0 + jj] = (d2 > 0.f) ? sqrtf(d2) : 0.f;
      }
    }
  }
  __syncthreads();
  if (w != 0) return;          // wave 0 continues alone (no more barriers)

  // ---------------- clustering (single wave, lane l owns row l) -------------
  const int l = lane;
  volatile float* Dv = &Dw[0][0];
  int tl = labels[b * NPTS + l];

  // k = #unique labels (labels in [0,8))
  int kcnt = 0;
  #pragma unroll
  for (int vv = 0; vv < 8; ++vv)
    kcnt += (__ballot(tl == vv) != 0ull) ? 1 : 0;

  // own-row scan: sim/dis sums (true diag = 0 contributes 0/sim+1) + row min
  float simS = 0.f, disS = 0.f;
  int simC = 0;
  float mval = BIGF; int midx = 0;
  #pragma unroll 1
  for (int j = 0; j < NPTS; ++j) {
    float v = Dw[l][j];
    int tlj = __shfl(tl, j);
    if (tlj == tl) { simS += v; simC += 1; } else { disS += v; }
    if (j != l && v < mval) { mval = v; midx = j; }   // strict <: lowest j wins ties
  }
  Dv[l * 65 + l] = BIGF;       // reference inits diagonal to BIG

  unsigned long long actm = ~0ull;
  int cl = l;                  // cluster representative label
  const int merges = NPTS - kcnt;
  #pragma unroll 1
  for (int m = 0; m < merges; ++m) {
    // global argmin over rows' (minval, flat=l*64+midx), lowest-flat tie-break
    bool act = (actm >> l) & 1ull;
    float v = act ? mval : BIGF;
    int fi = (l << 6) | midx;
    #pragma unroll
    for (int off = 32; off; off >>= 1) {
      float ov = __shfl_xor(v, off);
      int of = __shfl_xor(fi, off);
      if (ov < v || (ov == v && of < fi)) { v = ov; fi = of; }
    }
    const int a = fi >> 6;     // a < bb guaranteed by symmetry + lowest-flat
    const int bb = fi & 63;

    // newrow[l] = min(Dw[a][l], Dw[b][l]) == min(Dw[l][a], Dw[l][b]) (symmetry)
    float va = Dv[l * 65 + a];
    float vb = Dv[l * 65 + bb];
    float nr = fminf(va, vb);
    Dv[l * 65 + a] = nr;       // col a
    Dv[a * 65 + l] = nr;       // row a

    actm &= ~(1ull << bb);
    if (cl == bb) cl = a;

    // per-row min maintenance (nr >= mval always; col bb removed, col a -> nr)
    act = (actm >> l) & 1ull;
    if (act && l != a) {
      if (midx == bb) midx = a;
      else if (nr == mval && a < midx) midx = a;
    }
    // fresh rescan for row a: candidates are the nr values across lanes
    float cv = (act && l != a) ? nr : BIGF;
    int cj = l;
    #pragma unroll
    for (int off = 32; off; off >>= 1) {
      float ov = __shfl_xor(cv, off);
      int oj = __shfl_xor(cj, off);
      if (ov < cv || (ov == cv && oj < cj)) { cv = ov; cj = oj; }
    }
    if (l == a) { mval = cv; midx = cj; }
  }

  // err count: adjacency(cl) XOR adjacency(tl)
  int ec = 0;
  #pragma unroll 1
  for (int j = 0; j < NPTS; ++j) {
    int clj = __shfl(cl, j);
    int tlj = __shfl(tl, j);
    ec += ((cl == clj) != (tl == tlj)) ? 1 : 0;
  }

  // wave reductions (deterministic butterfly)
  #pragma unroll
  for (int off = 32; off; off >>= 1) {
    simS += __shfl_xor(simS, off);
    disS += __shfl_xor(disS, off);
    simC += __shfl_xor(simC, off);
    ec   += __shfl_xor(ec, off);
  }
  if (l == 0) {
    simS_o[b] = simS; disS_o[b] = disS;
    simC_o[b] = simC; errC_o[b] = ec;
  }
}

__global__ __launch_bounds__(64) void finalize_kernel(
    const float* __restrict__ simS, const float* __restrict__ disS,
    const int* __restrict__ simC, const int* __restrict__ errC,
    float* __restrict__ out)
{
  const int l = threadIdx.x;
  double ss = 0.0, dd = 0.0, sc = 0.0, ec = 0.0;
  #pragma unroll
  for (int r = 0; r < 4; ++r) {
    int i = (r << 6) + l;      // fixed order -> deterministic
    ss += (double)simS[i];
    dd += (double)disS[i];
    sc += (double)simC[i];
    ec += (double)errC[i];
  }
  #pragma unroll
  for (int off = 32; off; off >>= 1) {
    ss += __shfl_xor(ss, off);
    dd += __shfl_xor(dd, off);
    sc += __shfl_xor(sc, off);
    ec += __shfl_xor(ec, off);
  }
  if (l == 0) {
    const double total = 256.0 * 4096.0;
    double ms = ss / sc;
    double md = dd / (total - sc);
    out[0] = (float)(ec / 256.0 + 0.5 * (ms - md));
  }
}

extern "C" void kernel_launch(void* const* d_in, const int* in_sizes, int n_in,
                              void* d_out, int out_size, void* d_ws, size_t ws_size,
                              hipStream_t stream) {
  const float* q      = (const float*)d_in[0];
  const float* psg    = (const float*)d_in[1];
  const int*   labels = (const int*)d_in[2];
  float* out = (float*)d_out;

  float* simS = (float*)d_ws;          // [256]
  float* disS = simS + 256;            // [256]
  int*   simC = (int*)(disS + 256);    // [256]
  int*   errC = simC + 256;            // [256]

  fused_kernel<<<NBLK, 256, 0, stream>>>(q, psg, labels, simS, disS, simC, errC);
  finalize_kernel<<<1, 64, 0, stream>>>(simS, disS, simC, errC, out);
}

// Round 2
// 104.193 us; speedup vs baseline: 1.1541x; 1.1541x over previous
//
#include <hip/hip_runtime.h>

// QuerySpecificClusterModel: B=256 samples, n=64 points, d=768.
// Round 2: DPP-based argmin for clustering (all-VALU, ~90cyc vs ~780 DS-shfl),
// non-volatile LDS merge loop, ballot label masks, 8-wave Gram with
// prefetched staging and fixed (row>>3) XOR swizzle.

#define NPTS 64
#define DIM 768
#define CH 128
#define NCH 6
#define NT 512
#define NW 8
#define BIGF 1e9f

// ---- DPP lexicographic argmin over 64 lanes: (val, flatidx), lowest idx tie ----
// ror 1,2,4,8 reduce each 16-row; bcast15 merges row pairs; bcast31 merges
// halves; global result lands in lane 63, broadcast via readlane.
template <int CTRL>
__device__ __forceinline__ void amin_step(float& vf, int& fi) {
  int sv = __builtin_amdgcn_update_dpp(__float_as_int(vf), __float_as_int(vf),
                                       CTRL, 0xF, 0xF, false);
  int si = __builtin_amdgcn_update_dpp(fi, fi, CTRL, 0xF, 0xF, false);
  float svf = __int_as_float(sv);
  bool take = (svf < vf) || (svf == vf && si < fi);
  vf = take ? svf : vf;
  fi = take ? si : fi;
}

__device__ __forceinline__ void argmin64(float& vf, int& fi) {
  amin_step<0x121>(vf, fi);   // row_ror:1
  amin_step<0x122>(vf, fi);   // row_ror:2
  amin_step<0x124>(vf, fi);   // row_ror:4
  amin_step<0x128>(vf, fi);   // row_ror:8
  amin_step<0x142>(vf, fi);   // row_bcast:15
  amin_step<0x143>(vf, fi);   // row_bcast:31
  vf = __int_as_float(__builtin_amdgcn_readlane(__float_as_int(vf), 63));
  fi = __builtin_amdgcn_readlane(fi, 63);
}

__global__ __launch_bounds__(NT) void fused_kernel(
    const float* __restrict__ q,      // [256,768]
    const float* __restrict__ psg,    // [256,64,768]
    const int*   __restrict__ labels, // [256,64]
    float* __restrict__ simS_o, float* __restrict__ disS_o,
    int* __restrict__ simC_o, int* __restrict__ errC_o)
{
  __shared__ __align__(16) float s[NPTS][132];   // staged scaled chunk (swizzled)
  __shared__ __align__(16) float Dw[NPTS][65];   // distance matrix
  __shared__ float diag[NPTS];
  __shared__ __align__(16) int cls[NPTS];

  const int b = blockIdx.x;
  const int t = threadIdx.x;
  const int w = t >> 6;          // wave id 0..7
  const int lane = t & 63;
  const int g = lane >> 3;
  const int h = lane & 7;
  const int i0 = g << 3;
  const int j0 = h << 3;

  const float* qb = q + (size_t)b * DIM;
  const float* pb = psg + (size_t)b * NPTS * DIM;

  float acc[8][8] = {};

  const int kvq = t & 31;        // float4 col within chunk (staging)
  const int irb = t >> 5;        // staging row base 0..15

  // prefetch chunk 0
  float4 qv, pv[4];
  qv = *reinterpret_cast<const float4*>(qb + (kvq << 2));
  #pragma unroll
  for (int r = 0; r < 4; ++r)
    pv[r] = *reinterpret_cast<const float4*>(pb + (size_t)(irb + (r << 4)) * DIM + (kvq << 2));

  for (int c = 0; c < NCH; ++c) {
    // write staged (scaled) chunk c; swizzle (i>>3) is distinct per g-group
    #pragma unroll
    for (int r = 0; r < 4; ++r) {
      int i = irb + (r << 4);
      float4 sv;
      sv.x = pv[r].x * qv.x; sv.y = pv[r].y * qv.y;
      sv.z = pv[r].z * qv.z; sv.w = pv[r].w * qv.w;
      *reinterpret_cast<float4*>(&s[i][(kvq ^ (i >> 3)) << 2]) = sv;
    }
    __syncthreads();
    // prefetch chunk c+1 (latency hides under compute below)
    if (c + 1 < NCH) {
      qv = *reinterpret_cast<const float4*>(qb + (c + 1) * CH + (kvq << 2));
      #pragma unroll
      for (int r = 0; r < 4; ++r)
        pv[r] = *reinterpret_cast<const float4*>(
            pb + (size_t)(irb + (r << 4)) * DIM + (c + 1) * CH + (kvq << 2));
    }
    // K split across 8 waves: wave w owns k4 = w*4 .. w*4+3
    #pragma unroll
    for (int kk = 0; kk < 4; ++kk) {
      int k4 = (w << 2) + kk;
      float4 a4[8];
      #pragma unroll
      for (int ii = 0; ii < 8; ++ii) {
        int row = i0 + ii;
        a4[ii] = *reinterpret_cast<const float4*>(&s[row][(k4 ^ (row >> 3)) << 2]);
      }
      #pragma unroll
      for (int jj = 0; jj < 8; ++jj) {
        int row = j0 + jj;
        float4 b4 = *reinterpret_cast<const float4*>(&s[row][(k4 ^ (row >> 3)) << 2]);
        #pragma unroll
        for (int ii = 0; ii < 8; ++ii) {
          acc[ii][jj] += a4[ii].x * b4.x;
          acc[ii][jj] += a4[ii].y * b4.y;
          acc[ii][jj] += a4[ii].z * b4.z;
          acc[ii][jj] += a4[ii].w * b4.w;
        }
      }
    }
    __syncthreads();
  }

  // Cross-wave reduction into wave 0 (fixed order src 1..7; XOR-swizzled slots)
  float* fs = &s[0][0];
  #pragma unroll 1
  for (int src = 1; src < NW; ++src) {
    if (w == src) {
      #pragma unroll
      for (int ii = 0; ii < 8; ++ii) {
        #pragma unroll
        for (int jq = 0; jq < 2; ++jq) {
          int slot = ii * 2 + jq;
          float4 vv = make_float4(acc[ii][jq * 4 + 0], acc[ii][jq * 4 + 1],
                                  acc[ii][jq * 4 + 2], acc[ii][jq * 4 + 3]);
          *reinterpret_cast<float4*>(&fs[(lane << 6) + ((slot ^ (lane & 7)) << 2)]) = vv;
        }
      }
    }
    __syncthreads();
    if (w == 0) {
      #pragma unroll
      for (int ii = 0; ii < 8; ++ii) {
        #pragma unroll
        for (int jq = 0; jq < 2; ++jq) {
          int slot = ii * 2 + jq;
          float4 vv = *reinterpret_cast<const float4*>(
              &fs[(lane << 6) + ((slot ^ (lane & 7)) << 2)]);
          acc[ii][jq * 4 + 0] += vv.x; acc[ii][jq * 4 + 1] += vv.y;
          acc[ii][jq * 4 + 2] += vv.z; acc[ii][jq * 4 + 3] += vv.w;
        }
      }
    }
    __syncthreads();
  }

  if (w != 0) return;            // wave 0 continues alone; same-wave LDS is in-order

  // diag (squared norms) then distances (diag exactly 0)
  if (g == h) {
    #pragma unroll
    for (int ii = 0; ii < 8; ++ii) diag[i0 + ii] = acc[ii][ii];
  }
  #pragma unroll
  for (int ii = 0; ii < 8; ++ii) {
    float di = diag[i0 + ii];
    #pragma unroll
    for (int jj = 0; jj < 8; ++jj) {
      float d2 = di + diag[j0 + jj] - 2.f * acc[ii][jj];
      d2 = fmaxf(d2, 0.f);
      Dw[i0 + ii][j0 + jj] = (d2 > 0.f) ? sqrtf(d2) : 0.f;
    }
  }

  // ---------------- clustering (single wave, lane l owns row l) -------------
  const int l = lane;
  float* Dm = &Dw[0][0];
  int tl = labels[b * NPTS + l];

  // label-equality mask + unique-label count via 8 ballots
  unsigned long long sMask = 0ull;
  int kcnt = 0;
  #pragma unroll
  for (int v = 0; v < 8; ++v) {
    unsigned long long mv = __ballot(tl == v);
    kcnt += (mv != 0ull) ? 1 : 0;
    if (tl == v) sMask = mv;
  }
  int simC = __popcll(sMask);

  // own-row scan: sim/dis sums + row min (strict <: lowest j wins ties)
  float simS = 0.f, disS = 0.f;
  float mval = BIGF; int midx = 0;
  const float* rowp = Dm + l * 65;
  #pragma unroll
  for (int j = 0; j < NPTS; ++j) {
    float v = rowp[j];
    bool sim = (sMask >> j) & 1ull;
    simS += sim ? v : 0.f;
    disS += sim ? 0.f : v;
    bool better = (j != l) && (v < mval);
    mval = better ? v : mval;
    midx = better ? j : midx;
  }
  Dm[l * 65 + l] = BIGF;         // reference inits diagonal to BIG

  unsigned long long actm = ~0ull;
  int cl = l;
  const int merges = NPTS - kcnt;
  #pragma unroll 1
  for (int m = 0; m < merges; ++m) {
    // global argmin over rows' (minval, flat=l*64+midx), lowest-flat tie-break
    bool act = (actm >> l) & 1ull;
    float vf = act ? mval : BIGF;
    int fi = (l << 6) | midx;
    argmin64(vf, fi);            // uniform result in all lanes
    const int a = fi >> 6;       // a < bb by symmetry + lowest-flat
    const int bb = fi & 63;

    // newrow[l] = min(D[l][a], D[l][bb]); update col a and row a
    float va = Dm[l * 65 + a];
    float vb = Dm[l * 65 + bb];
    float nr = fminf(va, vb);
    Dm[l * 65 + a] = nr;
    Dm[a * 65 + l] = nr;

    actm &= ~(1ull << bb);
    cl = (cl == bb) ? a : cl;

    // per-row min maintenance (nr >= mval always; col bb removed, col a -> nr)
    bool actrow = ((actm >> l) & 1ull) && (l != a);
    if (actrow) {
      if (midx == bb) midx = a;
      else if (nr == mval && a < midx) midx = a;
    }
    // fresh rescan for row a: candidates are nr across active lanes != a
    float cv = actrow ? nr : BIGF;
    int cj = l;
    argmin64(cv, cj);
    if (l == a) { mval = cv; midx = cj; }
  }

  // err count via masks: ec = popcount(clusterMask XOR labelMask)
  cls[l] = cl;
  unsigned long long cMask = 0ull;
  const int4* cp = reinterpret_cast<const int4*>(cls);
  #pragma unroll
  for (int jq = 0; jq < 16; ++jq) {
    int4 c4 = cp[jq];
    cMask |= ((unsigned long long)(c4.x == cl)) << (jq * 4 + 0);
    cMask |= ((unsigned long long)(c4.y == cl)) << (jq * 4 + 1);
    cMask |= ((unsigned long long)(c4.z == cl)) << (jq * 4 + 2);
    cMask |= ((unsigned long long)(c4.w == cl)) << (jq * 4 + 3);
  }
  int ec = __popcll(cMask ^ sMask);

  // wave reductions (deterministic butterfly; one-time)
  #pragma unroll
  for (int off = 32; off; off >>= 1) {
    simS += __shfl_xor(simS, off);
    disS += __shfl_xor(disS, off);
    simC += __shfl_xor(simC, off);
    ec   += __shfl_xor(ec, off);
  }
  if (l == 0) {
    simS_o[b] = simS; disS_o[b] = disS;
    simC_o[b] = simC; errC_o[b] = ec;
  }
}

__global__ __launch_bounds__(64) void finalize_kernel(
    const float* __restrict__ simS, const float* __restrict__ disS,
    const int* __restrict__ simC, const int* __restrict__ errC,
    float* __restrict__ out)
{
  const int l = threadIdx.x;
  double ss = 0.0, dd = 0.0, sc = 0.0, ec = 0.0;
  #pragma unroll
  for (int r = 0; r < 4; ++r) {
    int i = (r << 6) + l;        // fixed order -> deterministic
    ss += (double)simS[i];
    dd += (double)disS[i];
    sc += (double)simC[i];
    ec += (double)errC[i];
  }
  #pragma unroll
  for (int off = 32; off; off >>= 1) {
    ss += __shfl_xor(ss, off);
    dd += __shfl_xor(dd, off);
    sc += __shfl_xor(sc, off);
    ec += __shfl_xor(ec, off);
  }
  if (l == 0) {
    const double total = 256.0 * 4096.0;
    double ms = ss / sc;
    double md = dd / (total - sc);
    out[0] = (float)(ec / 256.0 + 0.5 * (ms - md));
  }
}

extern "C" void kernel_launch(void* const* d_in, const int* in_sizes, int n_in,
                              void* d_out, int out_size, void* d_ws, size_t ws_size,
                              hipStream_t stream) {
  const float* q      = (const float*)d_in[0];
  const float* psg    = (const float*)d_in[1];
  const int*   labels = (const int*)d_in[2];
  float* out = (float*)d_out;

  float* simS = (float*)d_ws;          // [256]
  float* disS = simS + 256;            // [256]
  int*   simC = (int*)(disS + 256);    // [256]
  int*   errC = simC + 256;            // [256]

  fused_kernel<<<256, NT, 0, stream>>>(q, psg, labels, simS, disS, simC, errC);
  finalize_kernel<<<1, 64, 0, stream>>>(simS, disS, simC, errC, out);
}